// Round 14
// baseline (127.147 us; speedup 1.0000x reference)
//
#include <hip/hip_runtime.h>

// KAN B-spline activation, cubic, G=5, F=768 — Round 14: DIAGNOSTIC.
// R13 finally executed the R6 design: dur 108.6us => kan_main ~= 29-32us
// inferred, ~2x the memory floor, with BOTH pipes modeled <8us and occupancy
// (12 vs 24 waves/CU across R13/R3) not mattering. Our dispatch is hidden
// from rocprof top-5 (all slots are 42us harness fills), so theories keep
// failing unfalsified.
//
// This round launches kan_main TWICE (idempotent: reads x/ws only, writes
// identical out both times). Marginal cost of the 2nd (warm-x) dispatch:
//     delta = dur_R14 - dur_R13  = kan_main with x L3-resident.
// Branch A (delta >= 25us): internally bound -> ablate eval phases next.
// Branch B (delta <= 15us): cold-read HBM inefficiency -> restructure
// streaming next. Kernel code itself is byte-identical to R13.

constexpr int FEAT  = 768;
constexpr int GSZ   = 5;
constexpr int NCOEF = 7;
constexpr int TPF   = 13;          // padded per-feature table: 0,0,0,c0..c6,0,0,0
constexpr int BLK   = 256;
constexpr int NBLK  = 768;         // 3 blocks/CU exactly; threads*4 ≡ 0 mod 768

// ws SoA rows (each FEAT floats): 0=invh, 1=nt0h, 2..8=coeff*scaler
__global__ __launch_bounds__(256)
void kan_precompute(const float* __restrict__ knots,
                    const float* __restrict__ coeffs,
                    const float* __restrict__ scaler,
                    float* __restrict__ ws)
{
    const int f = blockIdx.x * blockDim.x + threadIdx.x;
    if (f >= FEAT) return;
    const float k0 = knots[f * GSZ];
    const float k4 = knots[f * GSZ + GSZ - 1];
    const float h  = (k4 - k0) * 0.25f;
    const float iv = 1.0f / h;
    ws[0 * FEAT + f] = iv;
    ws[1 * FEAT + f] = 3.0f - k0 * iv;          // g = (x - (k0-3h))/h
    const float sc = scaler[f];
#pragma unroll
    for (int j = 0; j < NCOEF; ++j)
        ws[(2 + j) * FEAT + f] = coeffs[f * NCOEF + j] * sc;
}

__global__ __launch_bounds__(256)
void kan_main(const float* __restrict__ xg,
              const float* __restrict__ ws,
              float* __restrict__ outg,
              long n4)                           // float4 count
{
    __shared__ float clds[4 * TPF * BLK];        // 53,248 B -> 3 blocks/CU

    const int  t  = threadIdx.x;
    const long e0 = (long)blockIdx.x * BLK + t;  // float4 index
    const int  f0 = (int)((4 * e0) % FEAT);      // multiple of 4, FIXED
    const int  fq = f0 >> 2;                     // float4 column in ws rows

    // ---- coalesced preamble: 9 float4 loads (16B/lane) ----
    const float4* __restrict__ wsv = (const float4*)ws;   // rows of FEAT/4=192
    const float4 ivv = wsv[0 * (FEAT / 4) + fq];
    const float4 ntv = wsv[1 * (FEAT / 4) + fq];
    const float invh[4] = {ivv.x, ivv.y, ivv.z, ivv.w};
    const float nt0h[4] = {ntv.x, ntv.y, ntv.z, ntv.w};
#pragma unroll
    for (int j = 0; j < NCOEF; ++j) {
        const float4 cv = wsv[(2 + j) * (FEAT / 4) + fq];
        clds[(0 * TPF + 3 + j) * BLK + t] = cv.x;
        clds[(1 * TPF + 3 + j) * BLK + t] = cv.y;
        clds[(2 * TPF + 3 + j) * BLK + t] = cv.z;
        clds[(3 * TPF + 3 + j) * BLK + t] = cv.w;
    }
#pragma unroll
    for (int c = 0; c < 4; ++c)
#pragma unroll
        for (int j = 0; j < 3; ++j) {
            clds[(c * TPF + j)      * BLK + t] = 0.0f;   // left pad
            clds[(c * TPF + 10 + j) * BLK + t] = 0.0f;   // right pad
        }
    __syncthreads();

    auto eval = [&](float x, int c) -> float {   // c is compile-time constant
        const float g  = fmaf(x, invh[c], nt0h[c]);
        const float fi = floorf(g);
        const int   i  = (int)fi;
        const float w  = g - fi;
        const bool  inr = ((unsigned)i < 10u);   // spans 0..9 produce output
        const int   ic  = min(max(i, 0), 9);
        const float o  = 1.0f - w;
        const float w2 = w * w,  w3 = w2 * w;
        const float o2 = o * o,  o3 = o2 * o;
        const float W0 = o3 * (1.0f / 6.0f);
        const float W3 = w3 * (1.0f / 6.0f);
        const float W1 = fmaf(0.5f, w3, 2.0f / 3.0f) - w2;
        const float W2 = fmaf(0.5f, o3, 2.0f / 3.0f) - o2;
        const float* p = &clds[(c * TPF + ic) * BLK + t];
        float acc =      W0 * p[0];
        acc = fmaf(W1, p[BLK],     acc);
        acc = fmaf(W2, p[2 * BLK], acc);
        acc = fmaf(W3, p[3 * BLK], acc);
        return inr ? acc : 0.0f;
    };

    const float4* __restrict__ xp = (const float4*)xg;
    float4*       __restrict__ op = (float4*)outg;
    const long stride = (long)NBLK * BLK;        // 196,608 float4s

    long e = e0;
    for (; e + 3 * stride < n4; e += 4 * stride) {
        const float4 v0 = xp[e];
        const float4 v1 = xp[e + stride];
        const float4 v2 = xp[e + 2 * stride];
        const float4 v3 = xp[e + 3 * stride];
        float4 r0, r1, r2, r3;
        r0.x = eval(v0.x, 0); r0.y = eval(v0.y, 1);
        r0.z = eval(v0.z, 2); r0.w = eval(v0.w, 3);
        r1.x = eval(v1.x, 0); r1.y = eval(v1.y, 1);
        r1.z = eval(v1.z, 2); r1.w = eval(v1.w, 3);
        r2.x = eval(v2.x, 0); r2.y = eval(v2.y, 1);
        r2.z = eval(v2.z, 2); r2.w = eval(v2.w, 3);
        r3.x = eval(v3.x, 0); r3.y = eval(v3.y, 1);
        r3.z = eval(v3.z, 2); r3.w = eval(v3.w, 3);
        op[e]              = r0;
        op[e + stride]     = r1;
        op[e + 2 * stride] = r2;
        op[e + 3 * stride] = r3;
    }
    for (; e < n4; e += stride) {                // residual (empty: 16 = 4*4)
        const float4 v = xp[e];
        float4 r;
        r.x = eval(v.x, 0); r.y = eval(v.y, 1);
        r.z = eval(v.z, 2); r.w = eval(v.w, 3);
        op[e] = r;
    }
}

extern "C" void kernel_launch(void* const* d_in, const int* in_sizes, int n_in,
                              void* d_out, int out_size, void* d_ws, size_t ws_size,
                              hipStream_t stream) {
    const float* x      = (const float*)d_in[0];
    const float* knots  = (const float*)d_in[1];
    const float* coeffs = (const float*)d_in[2];
    const float* scaler = (const float*)d_in[3];
    float* out = (float*)d_out;
    float* ws  = (float*)d_ws;                   // uses 9*768*4 = 27.6 KB

    const long n4 = (long)in_sizes[0] / 4;

    kan_precompute<<<dim3((FEAT + 255) / 256), dim3(256), 0, stream>>>(
        knots, coeffs, scaler, ws);

    // Dispatch 1: cold x (L3 was just flushed by the harness's 268MB ws fill)
    kan_main<<<dim3(NBLK), dim3(BLK), 0, stream>>>(x, ws, out, n4);
    // Dispatch 2 (DIAGNOSTIC): identical work, warm x. Marginal dur vs R13
    // isolates kan_main's non-cold-read cost. Idempotent: same out values.
    kan_main<<<dim3(NBLK), dim3(BLK), 0, stream>>>(x, ws, out, n4);
}